// Round 4
// baseline (328.439 us; speedup 1.0000x reference)
//
#include <hip/hip_runtime.h>

// SocialPoolingLayer: fused edge-MLP (relu(pair@W1+b1)@W2+b2, sigmoid gate, elemwise
// product) + scatter-mean by src node.
// Round 4: (a) node_emb pre-converted to bf16 once (staging = pure 16B loads, no VALU
// convert, half the gather bytes); (b) ALL __syncthreads removed from main kernel --
// every LDS row is wave-local (wave w owns edge rows 16w..16w+15); (c) gated/pairA
// LDS union (26.9 KB -> 5 blocks/CU); (d) pre-pass diet: 1-kernel scan, off[] doubles
// as scatter cursor, fused pack+convert, int4 hist/scatter, float4 finalize.

typedef unsigned short ushort_t;
typedef __attribute__((ext_vector_type(8))) short     bf16x8;   // 8 bf16 = 4 VGPRs
typedef __attribute__((ext_vector_type(8))) unsigned short u16x8;
typedef __attribute__((ext_vector_type(4))) float     f32x4;

constexpr int D        = 64;
constexpr int TILE     = 64;     // edges per block (4 waves x 16 edges)
constexpr int BLOCK    = 256;
constexpr int PAIR_STR = 136;    // pair row stride in bf16 (128+8), 272 B
constexpr int H_STR    = 72;     // h/interaction row stride in bf16 (64+8), 144 B
constexpr int G_STR    = 68;     // gated row stride in f32 (64+4), 272 B (== PAIR_STR*2B)
constexpr int NFRAG    = 32;     // 16 (W1) + 8 (W2) + 8 (Wg) B-fragments

static __device__ __forceinline__ ushort_t f2bf(float f) {
    union { float f; unsigned int u; } v; v.f = f;
    const unsigned int r = v.u + 0x7FFFu + ((v.u >> 16) & 1u);   // RNE
    return (ushort_t)(r >> 16);
}

// ---------------- prep: pack weights (blocks 0..63) + node_emb -> bf16 ----------------
// Weight fragment layout (verified R3): frag f, lane l, elem j -> W[k][n],
// k = kc*32 + (l>>4)*8 + j, n = nt*16 + (l&15).

__global__ void prep_kernel(const float* __restrict__ W1, const float* __restrict__ W2,
                            const float* __restrict__ Wg, const float* __restrict__ emb,
                            ushort_t* __restrict__ wpack, ushort_t* __restrict__ emb_bf,
                            int total_emb) {
    if (blockIdx.x < 64) {                       // 64*256 == NFRAG*512 exactly
        const int t = blockIdx.x * 256 + threadIdx.x;
        const int f = t >> 9;
        const int l = (t >> 3) & 63;
        const int j = t & 7;
        const float* W; int nt, kc;
        if (f < 16)      { W = W1; nt = f >> 2;        kc = f & 3; }
        else if (f < 24) { W = W2; nt = (f - 16) >> 1; kc = (f - 16) & 1; }
        else             { W = Wg; nt = (f - 24) >> 1; kc = (f - 24) & 1; }
        const int k = kc * 32 + (l >> 4) * 8 + j;
        const int n = nt * 16 + (l & 15);
        wpack[t] = f2bf(W[k * 64 + n]);
    } else {
        const int idx  = (blockIdx.x - 64) * 256 + threadIdx.x;
        const int base = idx * 8;
        if (base < total_emb) {
            const float4 a = *(const float4*)(emb + base);
            const float4 b = *(const float4*)(emb + base + 4);
            u16x8 p;
            p[0]=f2bf(a.x); p[1]=f2bf(a.y); p[2]=f2bf(a.z); p[3]=f2bf(a.w);
            p[4]=f2bf(b.x); p[5]=f2bf(b.y); p[6]=f2bf(b.z); p[7]=f2bf(b.w);
            *(u16x8*)(emb_bf + base) = p;
        }
    }
}

// ---------------- counting sort by src ----------------

__global__ void hist_kernel(const int* __restrict__ ei, int* __restrict__ cnt, int E) {
    const int e = (blockIdx.x * blockDim.x + threadIdx.x) * 4;
    if (e + 3 < E) {
        const int4 v = *(const int4*)(ei + e);
        atomicAdd(&cnt[v.x], 1); atomicAdd(&cnt[v.y], 1);
        atomicAdd(&cnt[v.z], 1); atomicAdd(&cnt[v.w], 1);
    } else {
        for (int k = e; k < E; ++k) atomicAdd(&cnt[ei[k]], 1);
    }
}

// single-workgroup exclusive scan of cnt[N] -> off[N]  (N <= 1024*per)
__global__ void scan_all(const int* __restrict__ cnt, int* __restrict__ off, int N) {
    __shared__ int part[1024];
    const int t   = threadIdx.x;
    const int per = (N + 1023) / 1024;
    const int lo  = t * per;
    const int hi  = min(lo + per, N);
    int sum = 0;
    for (int i = lo; i < hi; ++i) sum += cnt[i];
    part[t] = sum; __syncthreads();
    for (int d = 1; d < 1024; d <<= 1) {
        const int v = (t >= d) ? part[t - d] : 0;
        __syncthreads();
        part[t] += v;
        __syncthreads();
    }
    int run = (t > 0) ? part[t - 1] : 0;
    for (int i = lo; i < hi; ++i) { const int c = cnt[i]; off[i] = run; run += c; }
}

// off[] doubles as the insertion cursor (destroyed; not needed afterwards)
__global__ void scatter_idx(const int* __restrict__ ei, int* __restrict__ off,
                            int* __restrict__ sorted, int E) {
    const int e = (blockIdx.x * blockDim.x + threadIdx.x) * 4;
    if (e + 3 < E) {
        const int4 v = *(const int4*)(ei + e);
        sorted[atomicAdd(&off[v.x], 1)] = e;
        sorted[atomicAdd(&off[v.y], 1)] = e + 1;
        sorted[atomicAdd(&off[v.z], 1)] = e + 2;
        sorted[atomicAdd(&off[v.w], 1)] = e + 3;
    } else {
        for (int k = e; k < E; ++k) sorted[atomicAdd(&off[ei[k]], 1)] = k;
    }
}

// ---------------- fused MFMA MLP + segmented scatter (barrier-free) ----------------
// Wave w exclusively owns LDS rows 16w..16w+15 of every array below, so no
// __syncthreads is needed anywhere: all write->read dependencies are intra-wave and
// the compiler's lgkmcnt insertion orders them.

__global__ __launch_bounds__(BLOCK, 5)
void edge_mlp_mfma(const ushort_t* __restrict__ emb_bf,   // [N][64] bf16
                   const int*   __restrict__ edge_index,  // [2][E] flat
                   const int*   __restrict__ sorted,      // edge ids sorted by src
                   const ushort_t* __restrict__ wpack,    // 32 packed B-frags
                   const float* __restrict__ b1, const float* __restrict__ b2,
                   const float* __restrict__ bg,
                   float* __restrict__ summed,            // [N][D] pre-zeroed
                   int E)
{
    __shared__ union {
        ushort_t pairA[TILE][PAIR_STR];   // staging, consumed by GEMM1
        float    gated[TILE][G_STR];      // written after GEMM1 reads done (same rows)
    } u;                                  // 17408 B
    __shared__ ushort_t hA[TILE][H_STR];  //  9216 B (h, then interaction)
    __shared__ int      srcIds[TILE];

    const int tid = threadIdx.x;

    // ---- stage: pure 16B bf16 loads into A-layout (wave-local rows) ----
    {
        const int e = tid >> 2, q = tid & 3;      // e: edge slot, q: 16-elem quarter
        const int ide = blockIdx.x * TILE + e;
        if (ide < E) {
            const int eg = sorted[ide];
            const int s  = edge_index[eg];
            const int dn = edge_index[E + eg];
            if (q == 0) srcIds[e] = s;
            const ushort_t* sr = emb_bf + (size_t)s  * D + q * 16;
            const ushort_t* dr = emb_bf + (size_t)dn * D + q * 16;
            *(u16x8*)&u.pairA[e][q * 16]          = *(const u16x8*)sr;
            *(u16x8*)&u.pairA[e][q * 16 + 8]      = *(const u16x8*)(sr + 8);
            *(u16x8*)&u.pairA[e][64 + q * 16]     = *(const u16x8*)dr;
            *(u16x8*)&u.pairA[e][64 + q * 16 + 8] = *(const u16x8*)(dr + 8);
        } else {
            if (q == 0) srcIds[e] = -1;
            const u16x8 z = {0,0,0,0,0,0,0,0};
            *(u16x8*)&u.pairA[e][q * 16]          = z;
            *(u16x8*)&u.pairA[e][q * 16 + 8]      = z;
            *(u16x8*)&u.pairA[e][64 + q * 16]     = z;
            *(u16x8*)&u.pairA[e][64 + q * 16 + 8] = z;
        }
    }

    const int w    = tid >> 6;           // wave id: owns edge rows 16w..16w+15
    const int ln   = tid & 63;
    const int quad = ln >> 4;
    const int cn   = ln & 15;            // output col within N-tile / A-operand row
    const int mrow = 16 * w + cn;        // A-operand row this lane reads
    const int orow = 16 * w + quad * 4;  // C/D rows this lane holds (orow..orow+3)

    // ---- GEMM1: h = relu(pair @ W1 + b1), M=16 K=128 N=64 ----
    bf16x8 a1f[4];
#pragma unroll
    for (int kc = 0; kc < 4; ++kc)
        a1f[kc] = *(const bf16x8*)&u.pairA[mrow][kc * 32 + quad * 8];

    f32x4 acc1[4];
#pragma unroll
    for (int nt = 0; nt < 4; ++nt) {
        const float b = b1[nt * 16 + cn];
        acc1[nt] = (f32x4){b, b, b, b};
    }
#pragma unroll
    for (int nt = 0; nt < 4; ++nt)
#pragma unroll
        for (int kc = 0; kc < 4; ++kc) {
            const bf16x8 bf = *(const bf16x8*)(wpack + ((nt * 4 + kc) * 64 + ln) * 8);
            acc1[nt] = __builtin_amdgcn_mfma_f32_16x16x32_bf16(a1f[kc], bf, acc1[nt], 0, 0, 0);
        }
#pragma unroll
    for (int nt = 0; nt < 4; ++nt)
#pragma unroll
        for (int r = 0; r < 4; ++r)
            hA[orow + r][nt * 16 + cn] = f2bf(fmaxf(acc1[nt][r], 0.f));

    // ---- GEMM2: interaction = h @ W2 + b2, K=64 ----
    bf16x8 a2f[2];
#pragma unroll
    for (int kc = 0; kc < 2; ++kc)
        a2f[kc] = *(const bf16x8*)&hA[mrow][kc * 32 + quad * 8];

    f32x4 acc2[4];
#pragma unroll
    for (int nt = 0; nt < 4; ++nt) {
        const float b = b2[nt * 16 + cn];
        acc2[nt] = (f32x4){b, b, b, b};
    }
#pragma unroll
    for (int nt = 0; nt < 4; ++nt)
#pragma unroll
        for (int kc = 0; kc < 2; ++kc) {
            const bf16x8 bf = *(const bf16x8*)(wpack + ((16 + nt * 2 + kc) * 64 + ln) * 8);
            acc2[nt] = __builtin_amdgcn_mfma_f32_16x16x32_bf16(a2f[kc], bf, acc2[nt], 0, 0, 0);
        }
#pragma unroll
    for (int nt = 0; nt < 4; ++nt)
#pragma unroll
        for (int r = 0; r < 4; ++r)
            hA[orow + r][nt * 16 + cn] = f2bf(acc2[nt][r]);

    // ---- GEMM3: gate_pre = interaction @ Wg + bg, K=64 ----
    bf16x8 a3f[2];
#pragma unroll
    for (int kc = 0; kc < 2; ++kc)
        a3f[kc] = *(const bf16x8*)&hA[mrow][kc * 32 + quad * 8];

    f32x4 accg[4];
#pragma unroll
    for (int nt = 0; nt < 4; ++nt) {
        const float b = bg[nt * 16 + cn];
        accg[nt] = (f32x4){b, b, b, b};
    }
#pragma unroll
    for (int nt = 0; nt < 4; ++nt)
#pragma unroll
        for (int kc = 0; kc < 2; ++kc) {
            const bf16x8 bf = *(const bf16x8*)(wpack + ((24 + nt * 2 + kc) * 64 + ln) * 8);
            accg[nt] = __builtin_amdgcn_mfma_f32_16x16x32_bf16(a3f[kc], bf, accg[nt], 0, 0, 0);
        }

    // ---- gated = interaction * sigmoid(gate_pre) -> LDS (C-layout matches) ----
#pragma unroll
    for (int nt = 0; nt < 4; ++nt)
#pragma unroll
        for (int r = 0; r < 4; ++r) {
            const float g = 1.0f / (1.0f + __expf(-accg[nt][r]));
            u.gated[orow + r][nt * 16 + cn] = acc2[nt][r] * g;
        }

    // ---- per-wave segmented reduction over its 16 sorted rows ----
    {
        const int rbase = 16 * w;
        float run = 0.f;
        int   prev = srcIds[rbase];
#pragma unroll
        for (int i = 0; i < 16; ++i) {
            const int s = srcIds[rbase + i];      // wave-uniform
            const float v = u.gated[rbase + i][ln];
            if (s != prev) {
                if (prev >= 0) unsafeAtomicAdd(&summed[(size_t)prev * D + ln], run);
                run = 0.f;
                prev = s;
            }
            run += v;
        }
        if (prev >= 0) unsafeAtomicAdd(&summed[(size_t)prev * D + ln], run);
    }
}

__global__ void finalize_mean(float* __restrict__ out,
                              const int* __restrict__ cnt,
                              int total)
{
    const int b = (blockIdx.x * blockDim.x + threadIdx.x) * 4;
    if (b < total) {
        float4 v = *(float4*)&out[b];
        const float c = fmaxf((float)cnt[b >> 6], 1.0f);   // 4 elems share one node
        v.x /= c; v.y /= c; v.z /= c; v.w /= c;
        *(float4*)&out[b] = v;
    }
}

extern "C" void kernel_launch(void* const* d_in, const int* in_sizes, int n_in,
                              void* d_out, int out_size, void* d_ws, size_t ws_size,
                              hipStream_t stream) {
    const float* node_emb   = (const float*)d_in[0];
    const int*   edge_index = (const int*)d_in[1];
    const float* W1 = (const float*)d_in[2];
    const float* b1 = (const float*)d_in[3];
    const float* W2 = (const float*)d_in[4];
    const float* b2 = (const float*)d_in[5];
    const float* Wg = (const float*)d_in[6];
    const float* bg = (const float*)d_in[7];

    const int N = in_sizes[0] / D;
    const int E = in_sizes[1] / 2;
    const int total_emb = N * D;

    // ws layout: cnt[N] | off[N] | sorted[E] | wpack[16384 bf16] | emb_bf[N*64 bf16]
    int* cnt    = (int*)d_ws;
    int* off    = cnt + N;
    int* sorted = off + N;
    ushort_t* wpack  = (ushort_t*)(sorted + E);          // 32 KB
    ushort_t* emb_bf = wpack + NFRAG * 512;              // 6.4 MB

    float* summed = (float*)d_out;

    hipMemsetAsync(cnt, 0, sizeof(int) * (size_t)N, stream);
    hipMemsetAsync(summed, 0, sizeof(float) * (size_t)total_emb, stream);

    const int cvt_blocks = (total_emb / 8 + 255) / 256;
    prep_kernel<<<64 + cvt_blocks, 256, 0, stream>>>(W1, W2, Wg, node_emb,
                                                     wpack, emb_bf, total_emb);

    const int e4blocks = ((E + 3) / 4 + 255) / 256;
    hist_kernel<<<e4blocks, 256, 0, stream>>>(edge_index, cnt, E);
    scan_all   <<<1, 1024, 0, stream>>>(cnt, off, N);
    scatter_idx<<<e4blocks, 256, 0, stream>>>(edge_index, off, sorted, E);

    const int ntiles = (E + TILE - 1) / TILE;
    edge_mlp_mfma<<<ntiles, BLOCK, 0, stream>>>(emb_bf, edge_index, sorted, wpack,
                                                b1, b2, bg, summed, E);

    finalize_mean<<<(total_emb / 4 + 255) / 256, 256, 0, stream>>>(summed, cnt, total_emb);
}

// Round 5
// 262.994 us; speedup vs baseline: 1.2488x; 1.2488x over previous
//
#include <hip/hip_runtime.h>

// SocialPoolingLayer: fused edge-MLP (relu(pair@W1+b1)@W2+b2, sigmoid gate, elemwise
// product) + scatter-mean by src node.
// Round 5: (a) algebraic fold: gate_pre = h@(W2@Wg) + (b2@Wg+bg) -- GEMM2 and GEMM3
// share one A-fragment load, no interaction LDS round-trip; (b) R4's single-block
// scan_all regressed the tail (1-CU serial scan) -> revert to R2's parallel 3-kernel
// scan; (c) prep dispatch fuses weight-pack + W2Wg + bg' + emb->bf16 + edge histogram.

typedef unsigned short ushort_t;
typedef __attribute__((ext_vector_type(8))) short     bf16x8;   // 8 bf16 = 4 VGPRs
typedef __attribute__((ext_vector_type(8))) unsigned short u16x8;
typedef __attribute__((ext_vector_type(4))) float     f32x4;

constexpr int D        = 64;
constexpr int TILE     = 64;     // edges per block (4 waves x 16 edges)
constexpr int BLOCK    = 256;
constexpr int PAIR_STR = 136;    // pair row stride in bf16 (128+8), 272 B
constexpr int H_STR    = 72;     // h row stride in bf16 (64+8), 144 B
constexpr int G_STR    = 68;     // gated row stride in f32 (64+4), 272 B
constexpr int NFRAG    = 32;     // 16 (W1) + 8 (W2) + 8 (W2@Wg) B-fragments

static __device__ __forceinline__ ushort_t f2bf(float f) {
    union { float f; unsigned int u; } v; v.f = f;
    const unsigned int r = v.u + 0x7FFFu + ((v.u >> 16) & 1u);   // RNE
    return (ushort_t)(r >> 16);
}

// ---------------- prep: pack + W2Wg + bg' + emb->bf16 + histogram, one dispatch ----
// Weight fragment layout (verified R3): frag f, lane l, elem j -> W[k][n],
// k = kc*32 + (l>>4)*8 + j, n = nt*16 + (l&15).
// f in [0,16): W1 (nt=f>>2, kc=f&3); [16,24): W2; [24,32): W2@Wg (computed here).

__global__ void prep_kernel(const float* __restrict__ W1, const float* __restrict__ W2,
                            const float* __restrict__ Wg,
                            const float* __restrict__ b2, const float* __restrict__ bg,
                            const float* __restrict__ emb, const int* __restrict__ ei,
                            ushort_t* __restrict__ wpack, float* __restrict__ bgp,
                            ushort_t* __restrict__ emb_bf, int* __restrict__ cnt,
                            int total_emb, int cvt_blocks, int E) {
    const int bid = blockIdx.x;
    if (bid < 64) {                              // 64*256 == NFRAG*512: weight packing
        const int t = bid * 256 + threadIdx.x;
        const int f = t >> 9;
        const int l = (t >> 3) & 63;
        const int j = t & 7;
        const int k = ((f < 16) ? (f & 3) : ((f - 16) & 1)) * 32 + (l >> 4) * 8 + j;
        const int n = ((f < 16) ? (f >> 2) : (((f & 7)) >> 1)) * 16 + (l & 15);
        float v;
        if (f < 16)      v = W1[k * 64 + n];
        else if (f < 24) v = W2[k * 64 + n];
        else {                                   // (W2@Wg)[k][n]
            float s = 0.f;
            const float* wr = W2 + k * 64;
#pragma unroll 8
            for (int m = 0; m < 64; ++m) s += wr[m] * Wg[m * 64 + n];
            v = s;
        }
        wpack[t] = f2bf(v);
    } else if (bid < 64 + cvt_blocks) {          // node_emb -> bf16
        const int idx  = (bid - 64) * 256 + threadIdx.x;
        const int base = idx * 8;
        if (base < total_emb) {
            const float4 a = *(const float4*)(emb + base);
            const float4 b = *(const float4*)(emb + base + 4);
            u16x8 p;
            p[0]=f2bf(a.x); p[1]=f2bf(a.y); p[2]=f2bf(a.z); p[3]=f2bf(a.w);
            p[4]=f2bf(b.x); p[5]=f2bf(b.y); p[6]=f2bf(b.z); p[7]=f2bf(b.w);
            *(u16x8*)(emb_bf + base) = p;
        }
    } else if (bid == 64 + cvt_blocks) {         // bg' = b2@Wg + bg (fp32)
        const int n = threadIdx.x;
        if (n < 64) {
            float s = bg[n];
#pragma unroll 8
            for (int m = 0; m < 64; ++m) s += b2[m] * Wg[m * 64 + n];
            bgp[n] = s;
        }
    } else {                                     // edge histogram by src
        const int e = ((bid - 65 - cvt_blocks) * 256 + threadIdx.x) * 4;
        if (e + 3 < E) {
            const int4 v = *(const int4*)(ei + e);
            atomicAdd(&cnt[v.x], 1); atomicAdd(&cnt[v.y], 1);
            atomicAdd(&cnt[v.z], 1); atomicAdd(&cnt[v.w], 1);
        } else {
            for (int k = e; k < E; ++k) atomicAdd(&cnt[ei[k]], 1);
        }
    }
}

// ---------------- parallel 3-kernel exclusive scan (R2 structure) ----------------

__global__ void scan_block(const int* __restrict__ cnt, int* __restrict__ off,
                           int* __restrict__ bsum, int N) {
    __shared__ int s[256];
    const int t = threadIdx.x, i = blockIdx.x * 256 + t;
    const int x = (i < N) ? cnt[i] : 0;
    s[t] = x; __syncthreads();
    for (int d = 1; d < 256; d <<= 1) {
        const int v = (t >= d) ? s[t - d] : 0;
        __syncthreads();
        s[t] += v;
        __syncthreads();
    }
    if (i < N) off[i] = s[t] - x;
    if (t == 255) bsum[blockIdx.x] = s[255];
}

__global__ void scan_sums(int* __restrict__ bsum, int nb) {  // nb <= 256
    __shared__ int s[256];
    const int t = threadIdx.x;
    const int x = (t < nb) ? bsum[t] : 0;
    s[t] = x; __syncthreads();
    for (int d = 1; d < 256; d <<= 1) {
        const int v = (t >= d) ? s[t - d] : 0;
        __syncthreads();
        s[t] += v;
        __syncthreads();
    }
    if (t < nb) bsum[t] = s[t] - x;
}

__global__ void add_sums(int* __restrict__ off, const int* __restrict__ bsum, int N) {
    const int i = blockIdx.x * 256 + threadIdx.x;
    if (i < N) off[i] += bsum[blockIdx.x];
}

// off[] doubles as the insertion cursor (destroyed; not needed afterwards)
__global__ void scatter_idx(const int* __restrict__ ei, int* __restrict__ off,
                            int* __restrict__ sorted, int E) {
    const int e = (blockIdx.x * blockDim.x + threadIdx.x) * 4;
    if (e + 3 < E) {
        const int4 v = *(const int4*)(ei + e);
        sorted[atomicAdd(&off[v.x], 1)] = e;
        sorted[atomicAdd(&off[v.y], 1)] = e + 1;
        sorted[atomicAdd(&off[v.z], 1)] = e + 2;
        sorted[atomicAdd(&off[v.w], 1)] = e + 3;
    } else {
        for (int k = e; k < E; ++k) sorted[atomicAdd(&off[ei[k]], 1)] = k;
    }
}

// ---------------- fused MFMA MLP + segmented scatter (barrier-free) ----------------
// Wave w exclusively owns LDS rows 16w..16w+15 of every array, so no __syncthreads.

__global__ __launch_bounds__(BLOCK, 5)
void edge_mlp_mfma(const ushort_t* __restrict__ emb_bf,   // [N][64] bf16
                   const int*   __restrict__ edge_index,  // [2][E] flat
                   const int*   __restrict__ sorted,      // edge ids sorted by src
                   const ushort_t* __restrict__ wpack,    // 32 packed B-frags
                   const float* __restrict__ b1, const float* __restrict__ b2,
                   const float* __restrict__ bgp,         // b2@Wg + bg
                   float* __restrict__ summed,            // [N][D] pre-zeroed
                   int E)
{
    __shared__ union {
        ushort_t pairA[TILE][PAIR_STR];   // staging, consumed by GEMM1
        float    gated[TILE][G_STR];      // written after GEMM1 a1f reads done
    } u;                                  // 17408 B
    __shared__ ushort_t hA[TILE][H_STR];  //  9216 B (h only now)
    __shared__ int      srcIds[TILE];

    const int tid = threadIdx.x;

    // ---- stage: pure 16B bf16 loads into A-layout (wave-local rows) ----
    {
        const int e = tid >> 2, q = tid & 3;
        const int ide = blockIdx.x * TILE + e;
        if (ide < E) {
            const int eg = sorted[ide];
            const int s  = edge_index[eg];
            const int dn = edge_index[E + eg];
            if (q == 0) srcIds[e] = s;
            const ushort_t* sr = emb_bf + (size_t)s  * D + q * 16;
            const ushort_t* dr = emb_bf + (size_t)dn * D + q * 16;
            *(u16x8*)&u.pairA[e][q * 16]          = *(const u16x8*)sr;
            *(u16x8*)&u.pairA[e][q * 16 + 8]      = *(const u16x8*)(sr + 8);
            *(u16x8*)&u.pairA[e][64 + q * 16]     = *(const u16x8*)dr;
            *(u16x8*)&u.pairA[e][64 + q * 16 + 8] = *(const u16x8*)(dr + 8);
        } else {
            if (q == 0) srcIds[e] = -1;
            const u16x8 z = {0,0,0,0,0,0,0,0};
            *(u16x8*)&u.pairA[e][q * 16]          = z;
            *(u16x8*)&u.pairA[e][q * 16 + 8]      = z;
            *(u16x8*)&u.pairA[e][64 + q * 16]     = z;
            *(u16x8*)&u.pairA[e][64 + q * 16 + 8] = z;
        }
    }

    const int w    = tid >> 6;           // wave id: owns edge rows 16w..16w+15
    const int ln   = tid & 63;
    const int quad = ln >> 4;
    const int cn   = ln & 15;
    const int mrow = 16 * w + cn;        // A-operand row this lane reads
    const int orow = 16 * w + quad * 4;  // C/D rows this lane holds

    // ---- GEMM1: h = relu(pair @ W1 + b1), M=16 K=128 N=64 ----
    bf16x8 a1f[4];
#pragma unroll
    for (int kc = 0; kc < 4; ++kc)
        a1f[kc] = *(const bf16x8*)&u.pairA[mrow][kc * 32 + quad * 8];

    f32x4 acc1[4];
#pragma unroll
    for (int nt = 0; nt < 4; ++nt) {
        const float b = b1[nt * 16 + cn];
        acc1[nt] = (f32x4){b, b, b, b};
    }
#pragma unroll
    for (int nt = 0; nt < 4; ++nt)
#pragma unroll
        for (int kc = 0; kc < 4; ++kc) {
            const bf16x8 bf = *(const bf16x8*)(wpack + ((nt * 4 + kc) * 64 + ln) * 8);
            acc1[nt] = __builtin_amdgcn_mfma_f32_16x16x32_bf16(a1f[kc], bf, acc1[nt], 0, 0, 0);
        }
#pragma unroll
    for (int nt = 0; nt < 4; ++nt)
#pragma unroll
        for (int r = 0; r < 4; ++r)
            hA[orow + r][nt * 16 + cn] = f2bf(fmaxf(acc1[nt][r], 0.f));

    // ---- GEMM2+3 fused: interaction = h@W2 + b2 ; gate_pre = h@(W2Wg) + bg' ----
    bf16x8 a2f[2];
#pragma unroll
    for (int kc = 0; kc < 2; ++kc)
        a2f[kc] = *(const bf16x8*)&hA[mrow][kc * 32 + quad * 8];

    f32x4 acc2[4], accg[4];
#pragma unroll
    for (int nt = 0; nt < 4; ++nt) {
        const float b  = b2 [nt * 16 + cn];
        const float bG = bgp[nt * 16 + cn];
        acc2[nt] = (f32x4){b, b, b, b};
        accg[nt] = (f32x4){bG, bG, bG, bG};
    }
#pragma unroll
    for (int nt = 0; nt < 4; ++nt)
#pragma unroll
        for (int kc = 0; kc < 2; ++kc) {
            const bf16x8 bf2 = *(const bf16x8*)(wpack + ((16 + nt * 2 + kc) * 64 + ln) * 8);
            const bf16x8 bfg = *(const bf16x8*)(wpack + ((24 + nt * 2 + kc) * 64 + ln) * 8);
            acc2[nt] = __builtin_amdgcn_mfma_f32_16x16x32_bf16(a2f[kc], bf2, acc2[nt], 0, 0, 0);
            accg[nt] = __builtin_amdgcn_mfma_f32_16x16x32_bf16(a2f[kc], bfg, accg[nt], 0, 0, 0);
        }

    // ---- gated = interaction * sigmoid(gate_pre) -> LDS (C-layout) ----
#pragma unroll
    for (int nt = 0; nt < 4; ++nt)
#pragma unroll
        for (int r = 0; r < 4; ++r) {
            const float g = 1.0f / (1.0f + __expf(-accg[nt][r]));
            u.gated[orow + r][nt * 16 + cn] = acc2[nt][r] * g;
        }

    // ---- per-wave segmented reduction over its 16 sorted rows ----
    {
        const int rbase = 16 * w;
        float run = 0.f;
        int   prev = srcIds[rbase];
#pragma unroll
        for (int i = 0; i < 16; ++i) {
            const int s = srcIds[rbase + i];      // wave-uniform
            const float v = u.gated[rbase + i][ln];
            if (s != prev) {
                if (prev >= 0) unsafeAtomicAdd(&summed[(size_t)prev * D + ln], run);
                run = 0.f;
                prev = s;
            }
            run += v;
        }
        if (prev >= 0) unsafeAtomicAdd(&summed[(size_t)prev * D + ln], run);
    }
}

__global__ void finalize_mean(float* __restrict__ out,
                              const int* __restrict__ cnt,
                              int total)
{
    const int b = (blockIdx.x * blockDim.x + threadIdx.x) * 4;
    if (b < total) {
        float4 v = *(float4*)&out[b];
        const float c = fmaxf((float)cnt[b >> 6], 1.0f);
        v.x /= c; v.y /= c; v.z /= c; v.w /= c;
        *(float4*)&out[b] = v;
    }
}

extern "C" void kernel_launch(void* const* d_in, const int* in_sizes, int n_in,
                              void* d_out, int out_size, void* d_ws, size_t ws_size,
                              hipStream_t stream) {
    const float* node_emb   = (const float*)d_in[0];
    const int*   edge_index = (const int*)d_in[1];
    const float* W1 = (const float*)d_in[2];
    const float* b1 = (const float*)d_in[3];
    const float* W2 = (const float*)d_in[4];
    const float* b2 = (const float*)d_in[5];
    const float* Wg = (const float*)d_in[6];
    const float* bg = (const float*)d_in[7];

    const int N = in_sizes[0] / D;
    const int E = in_sizes[1] / 2;
    const int total_emb = N * D;

    // ws: cnt[N] | off[N] | bsum[256] | sorted[E] | bgp[64 f32] | wpack[16K bf16] | emb_bf
    int* cnt    = (int*)d_ws;
    int* off    = cnt + N;
    int* bsum   = off + N;
    int* sorted = bsum + 256;
    float* bgp  = (float*)(sorted + E);
    ushort_t* wpack  = (ushort_t*)(bgp + 64);
    ushort_t* emb_bf = wpack + NFRAG * 512;

    float* summed = (float*)d_out;

    hipMemsetAsync(cnt, 0, sizeof(int) * (size_t)N, stream);
    hipMemsetAsync(summed, 0, sizeof(float) * (size_t)total_emb, stream);

    const int cvt_blocks = (total_emb / 8 + 255) / 256;
    const int e4blocks   = ((E + 3) / 4 + 255) / 256;
    prep_kernel<<<64 + cvt_blocks + 1 + e4blocks, 256, 0, stream>>>(
        W1, W2, Wg, b2, bg, node_emb, edge_index,
        wpack, bgp, emb_bf, cnt, total_emb, cvt_blocks, E);

    const int nblocks = (N + 255) / 256;   // 196 (<= 256)
    scan_block <<<nblocks, 256, 0, stream>>>(cnt, off, bsum, N);
    scan_sums  <<<1,       256, 0, stream>>>(bsum, nblocks);
    add_sums   <<<nblocks, 256, 0, stream>>>(off, bsum, N);
    scatter_idx<<<e4blocks, 256, 0, stream>>>(edge_index, off, sorted, E);

    const int ntiles = (E + TILE - 1) / TILE;
    edge_mlp_mfma<<<ntiles, BLOCK, 0, stream>>>(emb_bf, edge_index, sorted, wpack,
                                                b1, b2, bgp, summed, E);

    finalize_mean<<<(total_emb / 4 + 255) / 256, 256, 0, stream>>>(summed, cnt, total_emb);
}

// Round 7
// 256.300 us; speedup vs baseline: 1.2815x; 1.0261x over previous
//
#include <hip/hip_runtime.h>

// SocialPoolingLayer: fused edge-MLP (relu(pair@W1+b1)@W2+b2, sigmoid gate, elemwise
// product) + scatter-mean by src node.
// Round 7: R6's post-timing divergence root-caused to workspace overflow: the new
// rcnt[N] array pushed the ws footprint 200KB past R5's proven extent; emb_bf's tail
// then clobbered adjacent harness allocations (pristine input copy) -> call 1 correct,
// all later calls deterministically wrong. Fix: drop rcnt[], compute 1/max(cnt,1) in
// staging from the retained cnt[] array. Layout is byte-identical to R5's (proven).
// Keeps R6's wins: per-wave LDS slab reuse (17.4 KB, 8 blocks/CU), 6 dispatches,
// mean-scale at flush, inline bsum prefix in scatter.

typedef unsigned short ushort_t;
typedef __attribute__((ext_vector_type(8))) short     bf16x8;   // 8 bf16 = 4 VGPRs
typedef __attribute__((ext_vector_type(8))) unsigned short u16x8;
typedef __attribute__((ext_vector_type(4))) float     f32x4;

constexpr int D        = 64;
constexpr int TILE     = 64;     // edges per block (4 waves x 16 edges)
constexpr int BLOCK    = 256;
constexpr int NFRAG    = 32;     // 16 (W1) + 8 (W2) + 8 (W2@Wg) B-fragments
constexpr int SLAB_B   = 4352;   // per-wave slab: 16 rows x 272 B
constexpr int PAIR_STR = 136;    // pair row stride (bf16): 272 B
constexpr int H_STR    = 72;     // h row stride (bf16): 144 B
constexpr int G_STR    = 68;     // gated row stride (f32): 272 B

static __device__ __forceinline__ ushort_t f2bf(float f) {
    union { float f; unsigned int u; } v; v.f = f;
    const unsigned int r = v.u + 0x7FFFu + ((v.u >> 16) & 1u);   // RNE
    return (ushort_t)(r >> 16);
}

// ---------------- prep: pack + W2Wg + bg' + emb->bf16 + histogram, one dispatch ----
// Weight fragment layout (verified R3): frag f, lane l, elem j -> W[k][n],
// k = kc*32 + (l>>4)*8 + j, n = nt*16 + (l&15).
// f in [0,16): W1; [16,24): W2; [24,32): W2@Wg (computed here).

__global__ void prep_kernel(const float* __restrict__ W1, const float* __restrict__ W2,
                            const float* __restrict__ Wg,
                            const float* __restrict__ b2, const float* __restrict__ bg,
                            const float* __restrict__ emb, const int* __restrict__ ei,
                            ushort_t* __restrict__ wpack, float* __restrict__ bgp,
                            ushort_t* __restrict__ emb_bf, int* __restrict__ cnt,
                            int total_emb, int cvt_blocks, int E) {
    const int bid = blockIdx.x;
    if (bid < 64) {                              // 64*256 == NFRAG*512: weight packing
        const int t = bid * 256 + threadIdx.x;
        const int f = t >> 9;
        const int l = (t >> 3) & 63;
        const int j = t & 7;
        const int k = ((f < 16) ? (f & 3) : ((f - 16) & 1)) * 32 + (l >> 4) * 8 + j;
        const int n = ((f < 16) ? (f >> 2) : (((f & 7)) >> 1)) * 16 + (l & 15);
        float v;
        if (f < 16)      v = W1[k * 64 + n];
        else if (f < 24) v = W2[k * 64 + n];
        else {                                   // (W2@Wg)[k][n]
            float s = 0.f;
            const float* wr = W2 + k * 64;
#pragma unroll 8
            for (int m = 0; m < 64; ++m) s += wr[m] * Wg[m * 64 + n];
            v = s;
        }
        wpack[t] = f2bf(v);
    } else if (bid < 64 + cvt_blocks) {          // node_emb -> bf16
        const int idx  = (bid - 64) * 256 + threadIdx.x;
        const int base = idx * 8;
        if (base < total_emb) {
            const float4 a = *(const float4*)(emb + base);
            const float4 b = *(const float4*)(emb + base + 4);
            u16x8 p;
            p[0]=f2bf(a.x); p[1]=f2bf(a.y); p[2]=f2bf(a.z); p[3]=f2bf(a.w);
            p[4]=f2bf(b.x); p[5]=f2bf(b.y); p[6]=f2bf(b.z); p[7]=f2bf(b.w);
            *(u16x8*)(emb_bf + base) = p;
        }
    } else if (bid == 64 + cvt_blocks) {         // bg' = b2@Wg + bg (fp32)
        const int n = threadIdx.x;
        if (n < 64) {
            float s = bg[n];
#pragma unroll 8
            for (int m = 0; m < 64; ++m) s += b2[m] * Wg[m * 64 + n];
            bgp[n] = s;
        }
    } else {                                     // edge histogram by src
        const int e = ((bid - 65 - cvt_blocks) * 256 + threadIdx.x) * 4;
        if (e + 3 < E) {
            const int4 v = *(const int4*)(ei + e);
            atomicAdd(&cnt[v.x], 1); atomicAdd(&cnt[v.y], 1);
            atomicAdd(&cnt[v.z], 1); atomicAdd(&cnt[v.w], 1);
        } else {
            for (int k = e; k < E; ++k) atomicAdd(&cnt[ei[k]], 1);
        }
    }
}

// ---------------- scan: per-block exclusive offsets + block sums ----------

__global__ void scan_block(const int* __restrict__ cnt, int* __restrict__ off,
                           int* __restrict__ bsum, int N) {
    __shared__ int s[256];
    const int t = threadIdx.x, i = blockIdx.x * 256 + t;
    const int x = (i < N) ? cnt[i] : 0;
    s[t] = x; __syncthreads();
    for (int d = 1; d < 256; d <<= 1) {
        const int v = (t >= d) ? s[t - d] : 0;
        __syncthreads();
        s[t] += v;
        __syncthreads();
    }
    if (i < N) off[i] = s[t] - x;                 // block-local exclusive prefix
    if (t == 255) bsum[blockIdx.x] = s[255];
}

// scatter with inline bsum prefix (nb <= 256); off[] doubles as insertion cursor
__global__ void scatter_idx(const int* __restrict__ ei, int* __restrict__ off,
                            const int* __restrict__ bsum, int* __restrict__ sorted,
                            int E, int nb) {
    __shared__ int pref[256];
    const int t = threadIdx.x;
    const int x = (t < nb) ? bsum[t] : 0;
    pref[t] = x; __syncthreads();
    for (int d = 1; d < 256; d <<= 1) {
        const int v = (t >= d) ? pref[t - d] : 0;
        __syncthreads();
        pref[t] += v;
        __syncthreads();
    }
    // pref[] now inclusive prefix of bsum; exclusive for block b is pref[b-1] (0 if b==0)
    const int e = (blockIdx.x * blockDim.x + t) * 4;
    if (e + 3 < E) {
        const int4 v = *(const int4*)(ei + e);
        const int bx = v.x >> 8, by = v.y >> 8, bz = v.z >> 8, bw = v.w >> 8;
        sorted[(bx ? pref[bx - 1] : 0) + atomicAdd(&off[v.x], 1)] = e;
        sorted[(by ? pref[by - 1] : 0) + atomicAdd(&off[v.y], 1)] = e + 1;
        sorted[(bz ? pref[bz - 1] : 0) + atomicAdd(&off[v.z], 1)] = e + 2;
        sorted[(bw ? pref[bw - 1] : 0) + atomicAdd(&off[v.w], 1)] = e + 3;
    } else {
        for (int k = e; k < E; ++k) {
            const int s = ei[k], b = s >> 8;
            sorted[(b ? pref[b - 1] : 0) + atomicAdd(&off[s], 1)] = k;
        }
    }
}

// ---------------- fused MFMA MLP + segmented scatter (barrier-free) ----------------
// Wave w exclusively owns its 4352B slab + srcIds/rcS rows 16w..16w+15. All LDS
// dependencies are intra-wave (issue-order DS pipe + compiler lgkmcnt waits), so
// pair -> h -> gated reuse one slab with no __syncthreads.

__global__ __launch_bounds__(BLOCK, 8)
void edge_mlp_mfma(const ushort_t* __restrict__ emb_bf,   // [N][64] bf16
                   const int*   __restrict__ edge_index,  // [2][E] flat
                   const int*   __restrict__ sorted,      // edge ids sorted by src
                   const ushort_t* __restrict__ wpack,    // 32 packed B-frags
                   const float* __restrict__ b1, const float* __restrict__ b2,
                   const float* __restrict__ bgp,         // b2@Wg + bg
                   const int*   __restrict__ cnt,         // per-node edge counts
                   float* __restrict__ summed,            // [N][D] pre-zeroed
                   int E)
{
    __shared__ char  slab[4][SLAB_B];    // 17408 B: per-wave pair/h/gated
    __shared__ int   srcIds[TILE];
    __shared__ float rcS[TILE];

    const int tid = threadIdx.x;

    // ---- stage: pure 16B bf16 loads into per-wave slab (pair layout) ----
    {
        const int e = tid >> 2, q = tid & 3;      // e: edge slot 0..63, q: 16-elem quarter
        ushort_t* prow = (ushort_t*)&slab[e >> 4][(e & 15) * (PAIR_STR * 2)];
        const int ide = blockIdx.x * TILE + e;
        if (ide < E) {
            const int eg = sorted[ide];
            const int s  = edge_index[eg];
            const int dn = edge_index[E + eg];
            if (q == 0) { srcIds[e] = s; rcS[e] = 1.0f / fmaxf((float)cnt[s], 1.0f); }
            const ushort_t* sr = emb_bf + (size_t)s  * D + q * 16;
            const ushort_t* dr = emb_bf + (size_t)dn * D + q * 16;
            *(u16x8*)&prow[q * 16]          = *(const u16x8*)sr;
            *(u16x8*)&prow[q * 16 + 8]      = *(const u16x8*)(sr + 8);
            *(u16x8*)&prow[64 + q * 16]     = *(const u16x8*)dr;
            *(u16x8*)&prow[64 + q * 16 + 8] = *(const u16x8*)(dr + 8);
        } else {
            if (q == 0) { srcIds[e] = -1; rcS[e] = 1.0f; }
            const u16x8 z = {0,0,0,0,0,0,0,0};
            *(u16x8*)&prow[q * 16]          = z;
            *(u16x8*)&prow[q * 16 + 8]      = z;
            *(u16x8*)&prow[64 + q * 16]     = z;
            *(u16x8*)&prow[64 + q * 16 + 8] = z;
        }
    }

    const int w    = tid >> 6;           // wave id: owns slab[w] + rows 16w..16w+15
    const int ln   = tid & 63;
    const int quad = ln >> 4;
    const int cn   = ln & 15;
    ushort_t* pairW = (ushort_t*)slab[w];   // [16][136]
    ushort_t* hW    = (ushort_t*)slab[w];   // [16][72]  (overwrites pair after a1f reads)
    float*    gW    = (float*)   slab[w];   // [16][68]  (overwrites h after a2f reads)

    // ---- GEMM1: h = relu(pair @ W1 + b1), M=16 K=128 N=64 ----
    bf16x8 a1f[4];
#pragma unroll
    for (int kc = 0; kc < 4; ++kc)
        a1f[kc] = *(const bf16x8*)&pairW[cn * PAIR_STR + kc * 32 + quad * 8];

    f32x4 acc1[4];
#pragma unroll
    for (int nt = 0; nt < 4; ++nt) {
        const float b = b1[nt * 16 + cn];
        acc1[nt] = (f32x4){b, b, b, b};
    }
#pragma unroll
    for (int nt = 0; nt < 4; ++nt)
#pragma unroll
        for (int kc = 0; kc < 4; ++kc) {
            const bf16x8 bf = *(const bf16x8*)(wpack + ((nt * 4 + kc) * 64 + ln) * 8);
            acc1[nt] = __builtin_amdgcn_mfma_f32_16x16x32_bf16(a1f[kc], bf, acc1[nt], 0, 0, 0);
        }
#pragma unroll
    for (int nt = 0; nt < 4; ++nt)
#pragma unroll
        for (int r = 0; r < 4; ++r)
            hW[(quad * 4 + r) * H_STR + nt * 16 + cn] = f2bf(fmaxf(acc1[nt][r], 0.f));

    // ---- GEMM2+3 fused: interaction = h@W2 + b2 ; gate_pre = h@(W2Wg) + bg' ----
    bf16x8 a2f[2];
#pragma unroll
    for (int kc = 0; kc < 2; ++kc)
        a2f[kc] = *(const bf16x8*)&hW[cn * H_STR + kc * 32 + quad * 8];

    f32x4 acc2[4], accg[4];
#pragma unroll
    for (int nt = 0; nt < 4; ++nt) {
        const float b  = b2 [nt * 16 + cn];
        const float bG = bgp[nt * 16 + cn];
        acc2[nt] = (f32x4){b, b, b, b};
        accg[nt] = (f32x4){bG, bG, bG, bG};
    }
#pragma unroll
    for (int nt = 0; nt < 4; ++nt)
#pragma unroll
        for (int kc = 0; kc < 2; ++kc) {
            const bf16x8 bf2 = *(const bf16x8*)(wpack + ((16 + nt * 2 + kc) * 64 + ln) * 8);
            const bf16x8 bfg = *(const bf16x8*)(wpack + ((24 + nt * 2 + kc) * 64 + ln) * 8);
            acc2[nt] = __builtin_amdgcn_mfma_f32_16x16x32_bf16(a2f[kc], bf2, acc2[nt], 0, 0, 0);
            accg[nt] = __builtin_amdgcn_mfma_f32_16x16x32_bf16(a2f[kc], bfg, accg[nt], 0, 0, 0);
        }

    // ---- gated = interaction * sigmoid(gate_pre) -> slab (C-layout) ----
#pragma unroll
    for (int nt = 0; nt < 4; ++nt)
#pragma unroll
        for (int r = 0; r < 4; ++r) {
            const float g = 1.0f / (1.0f + __expf(-accg[nt][r]));
            gW[(quad * 4 + r) * G_STR + nt * 16 + cn] = acc2[nt][r] * g;
        }

    // ---- per-wave segmented reduction over its 16 sorted rows (mean-scaled) ----
    {
        const int rbase = 16 * w;
        float run = 0.f;
        int   prev = srcIds[rbase];
        int   lastIdx = rbase;
#pragma unroll
        for (int i = 0; i < 16; ++i) {
            const int s = srcIds[rbase + i];      // wave-uniform
            const float v = gW[i * G_STR + ln];
            if (s != prev) {
                if (prev >= 0)
                    unsafeAtomicAdd(&summed[(size_t)prev * D + ln], run * rcS[lastIdx]);
                run = 0.f;
                prev = s;
            }
            run += v;
            lastIdx = rbase + i;
        }
        if (prev >= 0)
            unsafeAtomicAdd(&summed[(size_t)prev * D + ln], run * rcS[lastIdx]);
    }
}

extern "C" void kernel_launch(void* const* d_in, const int* in_sizes, int n_in,
                              void* d_out, int out_size, void* d_ws, size_t ws_size,
                              hipStream_t stream) {
    const float* node_emb   = (const float*)d_in[0];
    const int*   edge_index = (const int*)d_in[1];
    const float* W1 = (const float*)d_in[2];
    const float* b1 = (const float*)d_in[3];
    const float* W2 = (const float*)d_in[4];
    const float* b2 = (const float*)d_in[5];
    const float* Wg = (const float*)d_in[6];
    const float* bg = (const float*)d_in[7];

    const int N = in_sizes[0] / D;
    const int E = in_sizes[1] / 2;
    const int total_emb = N * D;

    // ws layout == R5's proven extent (10,034,048 B for N=50000, E=800000):
    // cnt[N] | off[N] | bsum[256] | sorted[E] | bgp[64 f32] | wpack[16K bf16] | emb_bf
    int* cnt    = (int*)d_ws;
    int* off    = cnt + N;
    int* bsum   = off + N;
    int* sorted = bsum + 256;
    float* bgp  = (float*)(sorted + E);
    ushort_t* wpack  = (ushort_t*)(bgp + 64);
    ushort_t* emb_bf = wpack + NFRAG * 512;

    float* summed = (float*)d_out;

    hipMemsetAsync(cnt, 0, sizeof(int) * (size_t)N, stream);
    hipMemsetAsync(summed, 0, sizeof(float) * (size_t)total_emb, stream);

    const int cvt_blocks = (total_emb / 8 + 255) / 256;
    const int e4blocks   = ((E + 3) / 4 + 255) / 256;
    prep_kernel<<<64 + cvt_blocks + 1 + e4blocks, 256, 0, stream>>>(
        W1, W2, Wg, b2, bg, node_emb, edge_index,
        wpack, bgp, emb_bf, cnt, total_emb, cvt_blocks, E);

    const int nblocks = (N + 255) / 256;   // 196 (must be <= 256 for inline prefix)
    scan_block <<<nblocks, 256, 0, stream>>>(cnt, off, bsum, N);
    scatter_idx<<<e4blocks, 256, 0, stream>>>(edge_index, off, bsum, sorted, E, nblocks);

    const int ntiles = (E + TILE - 1) / TILE;
    edge_mlp_mfma<<<ntiles, BLOCK, 0, stream>>>(emb_bf, edge_index, sorted, wpack,
                                                b1, b2, bgp, cnt, summed, E);
}

// Round 8
// 256.185 us; speedup vs baseline: 1.2820x; 1.0004x over previous
//
#include <hip/hip_runtime.h>

// SocialPoolingLayer: fused edge-MLP (relu(pair@W1+b1)@W2+b2, sigmoid gate, elemwise
// product) + scatter-mean by src node.
// Round 8: (a) R7's launch_bounds(256,8) capped the UNIFIED VGPR+AGPR file at 64/wave
// -> spills (VGPR 32, FETCH+20MB, WRITE+37MB, main 85.6->95.4us). Relax to (256,6):
// ~85-reg cap, est. need ~65, 6 blocks/CU. (b) scatter writes packed (src<<16|dst)
// (N<65536) so main staging is ONE coalesced 4B load instead of 3 chained gathers.
// Workspace layout byte-identical to R5/R7's proven extent.

typedef unsigned short ushort_t;
typedef __attribute__((ext_vector_type(8))) short     bf16x8;   // 8 bf16 = 4 VGPRs
typedef __attribute__((ext_vector_type(8))) unsigned short u16x8;
typedef __attribute__((ext_vector_type(4))) float     f32x4;

constexpr int D        = 64;
constexpr int TILE     = 64;     // edges per block (4 waves x 16 edges)
constexpr int BLOCK    = 256;
constexpr int NFRAG    = 32;     // 16 (W1) + 8 (W2) + 8 (W2@Wg) B-fragments
constexpr int SLAB_B   = 4352;   // per-wave slab: 16 rows x 272 B
constexpr int PAIR_STR = 136;    // pair row stride (bf16): 272 B
constexpr int H_STR    = 72;     // h row stride (bf16): 144 B
constexpr int G_STR    = 68;     // gated row stride (f32): 272 B

static __device__ __forceinline__ ushort_t f2bf(float f) {
    union { float f; unsigned int u; } v; v.f = f;
    const unsigned int r = v.u + 0x7FFFu + ((v.u >> 16) & 1u);   // RNE
    return (ushort_t)(r >> 16);
}

// ---------------- prep: pack + W2Wg + bg' + emb->bf16 + histogram, one dispatch ----
// Weight fragment layout (verified R3): frag f, lane l, elem j -> W[k][n],
// k = kc*32 + (l>>4)*8 + j, n = nt*16 + (l&15).
// f in [0,16): W1; [16,24): W2; [24,32): W2@Wg (computed here).

__global__ void prep_kernel(const float* __restrict__ W1, const float* __restrict__ W2,
                            const float* __restrict__ Wg,
                            const float* __restrict__ b2, const float* __restrict__ bg,
                            const float* __restrict__ emb, const int* __restrict__ ei,
                            ushort_t* __restrict__ wpack, float* __restrict__ bgp,
                            ushort_t* __restrict__ emb_bf, int* __restrict__ cnt,
                            int total_emb, int cvt_blocks, int E) {
    const int bid = blockIdx.x;
    if (bid < 64) {                              // 64*256 == NFRAG*512: weight packing
        const int t = bid * 256 + threadIdx.x;
        const int f = t >> 9;
        const int l = (t >> 3) & 63;
        const int j = t & 7;
        const int k = ((f < 16) ? (f & 3) : ((f - 16) & 1)) * 32 + (l >> 4) * 8 + j;
        const int n = ((f < 16) ? (f >> 2) : (((f & 7)) >> 1)) * 16 + (l & 15);
        float v;
        if (f < 16)      v = W1[k * 64 + n];
        else if (f < 24) v = W2[k * 64 + n];
        else {                                   // (W2@Wg)[k][n]
            float s = 0.f;
            const float* wr = W2 + k * 64;
#pragma unroll 8
            for (int m = 0; m < 64; ++m) s += wr[m] * Wg[m * 64 + n];
            v = s;
        }
        wpack[t] = f2bf(v);
    } else if (bid < 64 + cvt_blocks) {          // node_emb -> bf16
        const int idx  = (bid - 64) * 256 + threadIdx.x;
        const int base = idx * 8;
        if (base < total_emb) {
            const float4 a = *(const float4*)(emb + base);
            const float4 b = *(const float4*)(emb + base + 4);
            u16x8 p;
            p[0]=f2bf(a.x); p[1]=f2bf(a.y); p[2]=f2bf(a.z); p[3]=f2bf(a.w);
            p[4]=f2bf(b.x); p[5]=f2bf(b.y); p[6]=f2bf(b.z); p[7]=f2bf(b.w);
            *(u16x8*)(emb_bf + base) = p;
        }
    } else if (bid == 64 + cvt_blocks) {         // bg' = b2@Wg + bg (fp32)
        const int n = threadIdx.x;
        if (n < 64) {
            float s = bg[n];
#pragma unroll 8
            for (int m = 0; m < 64; ++m) s += b2[m] * Wg[m * 64 + n];
            bgp[n] = s;
        }
    } else {                                     // edge histogram by src
        const int e = ((bid - 65 - cvt_blocks) * 256 + threadIdx.x) * 4;
        if (e + 3 < E) {
            const int4 v = *(const int4*)(ei + e);
            atomicAdd(&cnt[v.x], 1); atomicAdd(&cnt[v.y], 1);
            atomicAdd(&cnt[v.z], 1); atomicAdd(&cnt[v.w], 1);
        } else {
            for (int k = e; k < E; ++k) atomicAdd(&cnt[ei[k]], 1);
        }
    }
}

// ---------------- scan: per-block exclusive offsets + block sums ----------

__global__ void scan_block(const int* __restrict__ cnt, int* __restrict__ off,
                           int* __restrict__ bsum, int N) {
    __shared__ int s[256];
    const int t = threadIdx.x, i = blockIdx.x * 256 + t;
    const int x = (i < N) ? cnt[i] : 0;
    s[t] = x; __syncthreads();
    for (int d = 1; d < 256; d <<= 1) {
        const int v = (t >= d) ? s[t - d] : 0;
        __syncthreads();
        s[t] += v;
        __syncthreads();
    }
    if (i < N) off[i] = s[t] - x;                 // block-local exclusive prefix
    if (t == 255) bsum[blockIdx.x] = s[255];
}

// scatter with inline bsum prefix (nb <= 256); off[] doubles as insertion cursor.
// Writes packed (src<<16)|dst per slot -- requires N < 65536.
__global__ void scatter_idx(const int* __restrict__ ei, int* __restrict__ off,
                            const int* __restrict__ bsum, unsigned* __restrict__ sorted,
                            int E, int nb) {
    __shared__ int pref[256];
    const int t = threadIdx.x;
    const int x = (t < nb) ? bsum[t] : 0;
    pref[t] = x; __syncthreads();
    for (int d = 1; d < 256; d <<= 1) {
        const int v = (t >= d) ? pref[t - d] : 0;
        __syncthreads();
        pref[t] += v;
        __syncthreads();
    }
    // pref[] inclusive prefix of bsum; exclusive for block b is pref[b-1] (0 if b==0)
    const int e = (blockIdx.x * blockDim.x + t) * 4;
    if (e + 3 < E) {
        const int4 v = *(const int4*)(ei + e);        // src
        const int4 d = *(const int4*)(ei + E + e);    // dst
        const int bx = v.x >> 8, by = v.y >> 8, bz = v.z >> 8, bw = v.w >> 8;
        sorted[(bx ? pref[bx - 1] : 0) + atomicAdd(&off[v.x], 1)] =
            ((unsigned)v.x << 16) | (unsigned)d.x;
        sorted[(by ? pref[by - 1] : 0) + atomicAdd(&off[v.y], 1)] =
            ((unsigned)v.y << 16) | (unsigned)d.y;
        sorted[(bz ? pref[bz - 1] : 0) + atomicAdd(&off[v.z], 1)] =
            ((unsigned)v.z << 16) | (unsigned)d.z;
        sorted[(bw ? pref[bw - 1] : 0) + atomicAdd(&off[v.w], 1)] =
            ((unsigned)v.w << 16) | (unsigned)d.w;
    } else {
        for (int k = e; k < E; ++k) {
            const int s = ei[k], b = s >> 8;
            sorted[(b ? pref[b - 1] : 0) + atomicAdd(&off[s], 1)] =
                ((unsigned)s << 16) | (unsigned)ei[E + k];
        }
    }
}

// ---------------- fused MFMA MLP + segmented scatter (barrier-free) ----------------
// Wave w exclusively owns its 4352B slab + srcIds/rcS rows 16w..16w+15. All LDS
// dependencies are intra-wave (issue-order DS pipe + compiler lgkmcnt waits), so
// pair -> h -> gated reuse one slab with no __syncthreads.

__global__ __launch_bounds__(BLOCK, 6)
void edge_mlp_mfma(const ushort_t* __restrict__ emb_bf,   // [N][64] bf16
                   const unsigned* __restrict__ sorted,   // packed (src<<16)|dst, sorted
                   const ushort_t* __restrict__ wpack,    // 32 packed B-frags
                   const float* __restrict__ b1, const float* __restrict__ b2,
                   const float* __restrict__ bgp,         // b2@Wg + bg
                   const int*   __restrict__ cnt,         // per-node edge counts
                   float* __restrict__ summed,            // [N][D] pre-zeroed
                   int E)
{
    __shared__ char  slab[4][SLAB_B];    // 17408 B: per-wave pair/h/gated
    __shared__ int   srcIds[TILE];
    __shared__ float rcS[TILE];

    const int tid = threadIdx.x;

    // ---- stage: one packed 4B load -> two 128B row gathers into per-wave slab ----
    {
        const int e = tid >> 2, q = tid & 3;      // e: edge slot 0..63, q: 16-elem quarter
        ushort_t* prow = (ushort_t*)&slab[e >> 4][(e & 15) * (PAIR_STR * 2)];
        const int ide = blockIdx.x * TILE + e;
        if (ide < E) {
            const unsigned p = sorted[ide];
            const int s  = (int)(p >> 16);
            const int dn = (int)(p & 0xFFFFu);
            if (q == 0) { srcIds[e] = s; rcS[e] = 1.0f / fmaxf((float)cnt[s], 1.0f); }
            const ushort_t* sr = emb_bf + (size_t)s  * D + q * 16;
            const ushort_t* dr = emb_bf + (size_t)dn * D + q * 16;
            *(u16x8*)&prow[q * 16]          = *(const u16x8*)sr;
            *(u16x8*)&prow[q * 16 + 8]      = *(const u16x8*)(sr + 8);
            *(u16x8*)&prow[64 + q * 16]     = *(const u16x8*)dr;
            *(u16x8*)&prow[64 + q * 16 + 8] = *(const u16x8*)(dr + 8);
        } else {
            if (q == 0) { srcIds[e] = -1; rcS[e] = 1.0f; }
            const u16x8 z = {0,0,0,0,0,0,0,0};
            *(u16x8*)&prow[q * 16]          = z;
            *(u16x8*)&prow[q * 16 + 8]      = z;
            *(u16x8*)&prow[64 + q * 16]     = z;
            *(u16x8*)&prow[64 + q * 16 + 8] = z;
        }
    }

    const int w    = tid >> 6;           // wave id: owns slab[w] + rows 16w..16w+15
    const int ln   = tid & 63;
    const int quad = ln >> 4;
    const int cn   = ln & 15;
    ushort_t* pairW = (ushort_t*)slab[w];   // [16][136]
    ushort_t* hW    = (ushort_t*)slab[w];   // [16][72]  (overwrites pair after a1f reads)
    float*    gW    = (float*)   slab[w];   // [16][68]  (overwrites h after a2f reads)

    // ---- GEMM1: h = relu(pair @ W1 + b1), M=16 K=128 N=64 ----
    bf16x8 a1f[4];
#pragma unroll
    for (int kc = 0; kc < 4; ++kc)
        a1f[kc] = *(const bf16x8*)&pairW[cn * PAIR_STR + kc * 32 + quad * 8];

    f32x4 acc1[4];
#pragma unroll
    for (int nt = 0; nt < 4; ++nt) {
        const float b = b1[nt * 16 + cn];
        acc1[nt] = (f32x4){b, b, b, b};
    }
#pragma unroll
    for (int nt = 0; nt < 4; ++nt)
#pragma unroll
        for (int kc = 0; kc < 4; ++kc) {
            const bf16x8 bf = *(const bf16x8*)(wpack + ((nt * 4 + kc) * 64 + ln) * 8);
            acc1[nt] = __builtin_amdgcn_mfma_f32_16x16x32_bf16(a1f[kc], bf, acc1[nt], 0, 0, 0);
        }
#pragma unroll
    for (int nt = 0; nt < 4; ++nt)
#pragma unroll
        for (int r = 0; r < 4; ++r)
            hW[(quad * 4 + r) * H_STR + nt * 16 + cn] = f2bf(fmaxf(acc1[nt][r], 0.f));

    // ---- GEMM2+3 fused: interaction = h@W2 + b2 ; gate_pre = h@(W2Wg) + bg' ----
    bf16x8 a2f[2];
#pragma unroll
    for (int kc = 0; kc < 2; ++kc)
        a2f[kc] = *(const bf16x8*)&hW[cn * H_STR + kc * 32 + quad * 8];

    f32x4 acc2[4], accg[4];
#pragma unroll
    for (int nt = 0; nt < 4; ++nt) {
        const float b  = b2 [nt * 16 + cn];
        const float bG = bgp[nt * 16 + cn];
        acc2[nt] = (f32x4){b, b, b, b};
        accg[nt] = (f32x4){bG, bG, bG, bG};
    }
#pragma unroll
    for (int nt = 0; nt < 4; ++nt)
#pragma unroll
        for (int kc = 0; kc < 2; ++kc) {
            const bf16x8 bf2 = *(const bf16x8*)(wpack + ((16 + nt * 2 + kc) * 64 + ln) * 8);
            const bf16x8 bfg = *(const bf16x8*)(wpack + ((24 + nt * 2 + kc) * 64 + ln) * 8);
            acc2[nt] = __builtin_amdgcn_mfma_f32_16x16x32_bf16(a2f[kc], bf2, acc2[nt], 0, 0, 0);
            accg[nt] = __builtin_amdgcn_mfma_f32_16x16x32_bf16(a2f[kc], bfg, accg[nt], 0, 0, 0);
        }

    // ---- gated = interaction * sigmoid(gate_pre) -> slab (C-layout) ----
#pragma unroll
    for (int nt = 0; nt < 4; ++nt)
#pragma unroll
        for (int r = 0; r < 4; ++r) {
            const float g = 1.0f / (1.0f + __expf(-accg[nt][r]));
            gW[(quad * 4 + r) * G_STR + nt * 16 + cn] = acc2[nt][r] * g;
        }

    // ---- per-wave segmented reduction over its 16 sorted rows (mean-scaled) ----
    {
        const int rbase = 16 * w;
        float run = 0.f;
        int   prev = srcIds[rbase];
        int   lastIdx = rbase;
#pragma unroll
        for (int i = 0; i < 16; ++i) {
            const int s = srcIds[rbase + i];      // wave-uniform
            const float v = gW[i * G_STR + ln];
            if (s != prev) {
                if (prev >= 0)
                    unsafeAtomicAdd(&summed[(size_t)prev * D + ln], run * rcS[lastIdx]);
                run = 0.f;
                prev = s;
            }
            run += v;
            lastIdx = rbase + i;
        }
        if (prev >= 0)
            unsafeAtomicAdd(&summed[(size_t)prev * D + ln], run * rcS[lastIdx]);
    }
}

extern "C" void kernel_launch(void* const* d_in, const int* in_sizes, int n_in,
                              void* d_out, int out_size, void* d_ws, size_t ws_size,
                              hipStream_t stream) {
    const float* node_emb   = (const float*)d_in[0];
    const int*   edge_index = (const int*)d_in[1];
    const float* W1 = (const float*)d_in[2];
    const float* b1 = (const float*)d_in[3];
    const float* W2 = (const float*)d_in[4];
    const float* b2 = (const float*)d_in[5];
    const float* Wg = (const float*)d_in[6];
    const float* bg = (const float*)d_in[7];

    const int N = in_sizes[0] / D;
    const int E = in_sizes[1] / 2;
    const int total_emb = N * D;

    // ws layout == R5/R7's proven extent (10,034,048 B for N=50000, E=800000):
    // cnt[N] | off[N] | bsum[256] | sorted[E u32] | bgp[64 f32] | wpack[16K bf16] | emb_bf
    int* cnt    = (int*)d_ws;
    int* off    = cnt + N;
    int* bsum   = off + N;
    unsigned* sorted = (unsigned*)(bsum + 256);
    float* bgp  = (float*)(sorted + E);
    ushort_t* wpack  = (ushort_t*)(bgp + 64);
    ushort_t* emb_bf = wpack + NFRAG * 512;

    float* summed = (float*)d_out;

    hipMemsetAsync(cnt, 0, sizeof(int) * (size_t)N, stream);
    hipMemsetAsync(summed, 0, sizeof(float) * (size_t)total_emb, stream);

    const int cvt_blocks = (total_emb / 8 + 255) / 256;
    const int e4blocks   = ((E + 3) / 4 + 255) / 256;
    prep_kernel<<<64 + cvt_blocks + 1 + e4blocks, 256, 0, stream>>>(
        W1, W2, Wg, b2, bg, node_emb, edge_index,
        wpack, bgp, emb_bf, cnt, total_emb, cvt_blocks, E);

    const int nblocks = (N + 255) / 256;   // 196 (must be <= 256 for inline prefix)
    scan_block <<<nblocks, 256, 0, stream>>>(cnt, off, bsum, N);
    scatter_idx<<<e4blocks, 256, 0, stream>>>(edge_index, off, bsum, sorted, E, nblocks);

    const int ntiles = (E + TILE - 1) / TILE;
    edge_mlp_mfma<<<ntiles, BLOCK, 0, stream>>>(emb_bf, sorted, wpack,
                                                b1, b2, bgp, cnt, summed, E);
}

// Round 9
// 245.256 us; speedup vs baseline: 1.3392x; 1.0446x over previous
//
#include <hip/hip_runtime.h>

// SocialPoolingLayer: fused edge-MLP (relu(pair@W1+b1)@W2+b2, sigmoid gate, elemwise
// product) + scatter-mean by src node.
// Round 9: (a) kc-outer MFMA loops shrink A-fragment live ranges -> fits the 64-reg
// unified cap, launch_bounds(256,8) = 8 blocks/CU (R7's spill was wide-live a-frags);
// (b) segmented flush in REGISTERS: cross-quad butterfly (__shfl_xor 16/32) replaces
// the gated->LDS round-trip + serial 16x LDS-read loop; (c) summed-zeroing folded into
// prep (one fewer graph node). Workspace layout byte-identical to R5/R7/R8's proven
// extent. Packed (src<<16|dst) sorted array kept from R8 (FETCH 127->30MB win).

typedef unsigned short ushort_t;
typedef __attribute__((ext_vector_type(8))) short     bf16x8;   // 8 bf16 = 4 VGPRs
typedef __attribute__((ext_vector_type(8))) unsigned short u16x8;
typedef __attribute__((ext_vector_type(4))) float     f32x4;

constexpr int D        = 64;
constexpr int TILE     = 64;     // edges per block (4 waves x 16 edges)
constexpr int BLOCK    = 256;
constexpr int NFRAG    = 32;     // 16 (W1) + 8 (W2) + 8 (W2@Wg) B-fragments
constexpr int SLAB_B   = 4352;   // per-wave slab: 16 rows x 272 B
constexpr int PAIR_STR = 136;    // pair row stride (bf16): 272 B
constexpr int H_STR    = 72;     // h row stride (bf16): 144 B

static __device__ __forceinline__ ushort_t f2bf(float f) {
    union { float f; unsigned int u; } v; v.f = f;
    const unsigned int r = v.u + 0x7FFFu + ((v.u >> 16) & 1u);   // RNE
    return (ushort_t)(r >> 16);
}

// ---- prep: pack + W2Wg + bg' + emb->bf16 + histogram + summed-zero, one dispatch ----
// Weight fragment layout (verified R3): frag f, lane l, elem j -> W[k][n],
// k = kc*32 + (l>>4)*8 + j, n = nt*16 + (l&15).
// f in [0,16): W1; [16,24): W2; [24,32): W2@Wg (computed here).

__global__ void prep_kernel(const float* __restrict__ W1, const float* __restrict__ W2,
                            const float* __restrict__ Wg,
                            const float* __restrict__ b2, const float* __restrict__ bg,
                            const float* __restrict__ emb, const int* __restrict__ ei,
                            ushort_t* __restrict__ wpack, float* __restrict__ bgp,
                            ushort_t* __restrict__ emb_bf, int* __restrict__ cnt,
                            float* __restrict__ summed,
                            int total_emb, int cvt_blocks, int e4blocks, int E) {
    const int bid = blockIdx.x;
    if (bid < 64) {                              // 64*256 == NFRAG*512: weight packing
        const int t = bid * 256 + threadIdx.x;
        const int f = t >> 9;
        const int l = (t >> 3) & 63;
        const int j = t & 7;
        const int k = ((f < 16) ? (f & 3) : ((f - 16) & 1)) * 32 + (l >> 4) * 8 + j;
        const int n = ((f < 16) ? (f >> 2) : (((f & 7)) >> 1)) * 16 + (l & 15);
        float v;
        if (f < 16)      v = W1[k * 64 + n];
        else if (f < 24) v = W2[k * 64 + n];
        else {                                   // (W2@Wg)[k][n]
            float s = 0.f;
            const float* wr = W2 + k * 64;
#pragma unroll 8
            for (int m = 0; m < 64; ++m) s += wr[m] * Wg[m * 64 + n];
            v = s;
        }
        wpack[t] = f2bf(v);
    } else if (bid < 64 + cvt_blocks) {          // node_emb -> bf16
        const int idx  = (bid - 64) * 256 + threadIdx.x;
        const int base = idx * 8;
        if (base < total_emb) {
            const float4 a = *(const float4*)(emb + base);
            const float4 b = *(const float4*)(emb + base + 4);
            u16x8 p;
            p[0]=f2bf(a.x); p[1]=f2bf(a.y); p[2]=f2bf(a.z); p[3]=f2bf(a.w);
            p[4]=f2bf(b.x); p[5]=f2bf(b.y); p[6]=f2bf(b.z); p[7]=f2bf(b.w);
            *(u16x8*)(emb_bf + base) = p;
        }
    } else if (bid == 64 + cvt_blocks) {         // bg' = b2@Wg + bg (fp32)
        const int n = threadIdx.x;
        if (n < 64) {
            float s = bg[n];
#pragma unroll 8
            for (int m = 0; m < 64; ++m) s += b2[m] * Wg[m * 64 + n];
            bgp[n] = s;
        }
    } else if (bid < 65 + cvt_blocks + e4blocks) {   // edge histogram by src
        const int e = ((bid - 65 - cvt_blocks) * 256 + threadIdx.x) * 4;
        if (e + 3 < E) {
            const int4 v = *(const int4*)(ei + e);
            atomicAdd(&cnt[v.x], 1); atomicAdd(&cnt[v.y], 1);
            atomicAdd(&cnt[v.z], 1); atomicAdd(&cnt[v.w], 1);
        } else {
            for (int k = e; k < E; ++k) atomicAdd(&cnt[ei[k]], 1);
        }
    } else {                                     // zero summed (consumed 2 nodes later)
        const int idx  = (bid - 65 - cvt_blocks - e4blocks) * 256 + threadIdx.x;
        const int base = idx * 4;
        if (base < total_emb)
            *(float4*)(summed + base) = (float4){0.f, 0.f, 0.f, 0.f};
    }
}

// ---------------- scan: per-block exclusive offsets + block sums ----------

__global__ void scan_block(const int* __restrict__ cnt, int* __restrict__ off,
                           int* __restrict__ bsum, int N) {
    __shared__ int s[256];
    const int t = threadIdx.x, i = blockIdx.x * 256 + t;
    const int x = (i < N) ? cnt[i] : 0;
    s[t] = x; __syncthreads();
    for (int d = 1; d < 256; d <<= 1) {
        const int v = (t >= d) ? s[t - d] : 0;
        __syncthreads();
        s[t] += v;
        __syncthreads();
    }
    if (i < N) off[i] = s[t] - x;                 // block-local exclusive prefix
    if (t == 255) bsum[blockIdx.x] = s[255];
}

// scatter with inline bsum prefix (nb <= 256); off[] doubles as insertion cursor.
// Writes packed (src<<16)|dst per slot -- requires N < 65536.
__global__ void scatter_idx(const int* __restrict__ ei, int* __restrict__ off,
                            const int* __restrict__ bsum, unsigned* __restrict__ sorted,
                            int E, int nb) {
    __shared__ int pref[256];
    const int t = threadIdx.x;
    const int x = (t < nb) ? bsum[t] : 0;
    pref[t] = x; __syncthreads();
    for (int d = 1; d < 256; d <<= 1) {
        const int v = (t >= d) ? pref[t - d] : 0;
        __syncthreads();
        pref[t] += v;
        __syncthreads();
    }
    // pref[] inclusive prefix of bsum; exclusive for block b is pref[b-1] (0 if b==0)
    const int e = (blockIdx.x * blockDim.x + t) * 4;
    if (e + 3 < E) {
        const int4 v = *(const int4*)(ei + e);        // src
        const int4 d = *(const int4*)(ei + E + e);    // dst
        const int bx = v.x >> 8, by = v.y >> 8, bz = v.z >> 8, bw = v.w >> 8;
        sorted[(bx ? pref[bx - 1] : 0) + atomicAdd(&off[v.x], 1)] =
            ((unsigned)v.x << 16) | (unsigned)d.x;
        sorted[(by ? pref[by - 1] : 0) + atomicAdd(&off[v.y], 1)] =
            ((unsigned)v.y << 16) | (unsigned)d.y;
        sorted[(bz ? pref[bz - 1] : 0) + atomicAdd(&off[v.z], 1)] =
            ((unsigned)v.z << 16) | (unsigned)d.z;
        sorted[(bw ? pref[bw - 1] : 0) + atomicAdd(&off[v.w], 1)] =
            ((unsigned)v.w << 16) | (unsigned)d.w;
    } else {
        for (int k = e; k < E; ++k) {
            const int s = ei[k], b = s >> 8;
            sorted[(b ? pref[b - 1] : 0) + atomicAdd(&off[s], 1)] =
                ((unsigned)s << 16) | (unsigned)ei[E + k];
        }
    }
}

// ---------------- fused MFMA MLP + register segmented scatter (barrier-free) --------
// Wave w exclusively owns its 4352B slab + srcIds/rcS rows 16w..16w+15. All LDS
// dependencies are intra-wave (issue-order DS pipe + compiler lgkmcnt waits), so
// pair -> h reuse one slab with no __syncthreads. Gated values never touch LDS:
// the segmented reduction runs in registers with cross-quad __shfl_xor butterflies.

__global__ __launch_bounds__(BLOCK, 8)
void edge_mlp_mfma(const ushort_t* __restrict__ emb_bf,   // [N][64] bf16
                   const unsigned* __restrict__ sorted,   // packed (src<<16)|dst, sorted
                   const ushort_t* __restrict__ wpack,    // 32 packed B-frags
                   const float* __restrict__ b1, const float* __restrict__ b2,
                   const float* __restrict__ bgp,         // b2@Wg + bg
                   const int*   __restrict__ cnt,         // per-node edge counts
                   float* __restrict__ summed,            // [N][D] pre-zeroed
                   int E)
{
    __shared__ char  slab[4][SLAB_B];    // 17408 B: per-wave pair then h
    __shared__ int   srcIds[TILE];
    __shared__ float rcS[TILE];

    const int tid = threadIdx.x;

    // ---- stage: one packed 4B load -> two 128B row gathers into per-wave slab ----
    {
        const int e = tid >> 2, q4 = tid & 3;     // e: edge slot 0..63, q4: 16-elem quarter
        ushort_t* prow = (ushort_t*)&slab[e >> 4][(e & 15) * (PAIR_STR * 2)];
        const int ide = blockIdx.x * TILE + e;
        if (ide < E) {
            const unsigned p = sorted[ide];
            const int s  = (int)(p >> 16);
            const int dn = (int)(p & 0xFFFFu);
            if (q4 == 0) { srcIds[e] = s; rcS[e] = 1.0f / fmaxf((float)cnt[s], 1.0f); }
            const ushort_t* sr = emb_bf + (size_t)s  * D + q4 * 16;
            const ushort_t* dr = emb_bf + (size_t)dn * D + q4 * 16;
            *(u16x8*)&prow[q4 * 16]          = *(const u16x8*)sr;
            *(u16x8*)&prow[q4 * 16 + 8]      = *(const u16x8*)(sr + 8);
            *(u16x8*)&prow[64 + q4 * 16]     = *(const u16x8*)dr;
            *(u16x8*)&prow[64 + q4 * 16 + 8] = *(const u16x8*)(dr + 8);
        } else {
            if (q4 == 0) { srcIds[e] = -1; rcS[e] = 1.0f; }
            const u16x8 z = {0,0,0,0,0,0,0,0};
            *(u16x8*)&prow[q4 * 16]          = z;
            *(u16x8*)&prow[q4 * 16 + 8]      = z;
            *(u16x8*)&prow[64 + q4 * 16]     = z;
            *(u16x8*)&prow[64 + q4 * 16 + 8] = z;
        }
    }

    const int w    = tid >> 6;           // wave id: owns slab[w] + rows 16w..16w+15
    const int ln   = tid & 63;
    const int quad = ln >> 4;
    const int cn   = ln & 15;
    ushort_t* pairW = (ushort_t*)slab[w];   // [16][136]
    ushort_t* hW    = (ushort_t*)slab[w];   // [16][72]  (overwrites pair after a1 reads)

    // ---- GEMM1: h = relu(pair @ W1 + b1), M=16 K=128 N=64 (kc-outer) ----
    f32x4 acc1[4];
#pragma unroll
    for (int nt = 0; nt < 4; ++nt) {
        const float b = b1[nt * 16 + cn];
        acc1[nt] = (f32x4){b, b, b, b};
    }
#pragma unroll
    for (int kc = 0; kc < 4; ++kc) {
        const bf16x8 a = *(const bf16x8*)&pairW[cn * PAIR_STR + kc * 32 + quad * 8];
#pragma unroll
        for (int nt = 0; nt < 4; ++nt) {
            const bf16x8 bf = *(const bf16x8*)(wpack + ((nt * 4 + kc) * 64 + ln) * 8);
            acc1[nt] = __builtin_amdgcn_mfma_f32_16x16x32_bf16(a, bf, acc1[nt], 0, 0, 0);
        }
    }
#pragma unroll
    for (int nt = 0; nt < 4; ++nt)
#pragma unroll
        for (int r = 0; r < 4; ++r)
            hW[(quad * 4 + r) * H_STR + nt * 16 + cn] = f2bf(fmaxf(acc1[nt][r], 0.f));

    // ---- GEMM2+3 fused (kc-outer): interaction = h@W2+b2 ; gate_pre = h@(W2Wg)+bg' ----
    f32x4 acc2[4], accg[4];
#pragma unroll
    for (int nt = 0; nt < 4; ++nt) {
        const float b  = b2 [nt * 16 + cn];
        const float bG = bgp[nt * 16 + cn];
        acc2[nt] = (f32x4){b, b, b, b};
        accg[nt] = (f32x4){bG, bG, bG, bG};
    }
#pragma unroll
    for (int kc = 0; kc < 2; ++kc) {
        const bf16x8 a = *(const bf16x8*)&hW[cn * H_STR + kc * 32 + quad * 8];
#pragma unroll
        for (int nt = 0; nt < 4; ++nt) {
            const bf16x8 bf2 = *(const bf16x8*)(wpack + ((16 + nt * 2 + kc) * 64 + ln) * 8);
            const bf16x8 bfg = *(const bf16x8*)(wpack + ((24 + nt * 2 + kc) * 64 + ln) * 8);
            acc2[nt] = __builtin_amdgcn_mfma_f32_16x16x32_bf16(a, bf2, acc2[nt], 0, 0, 0);
            accg[nt] = __builtin_amdgcn_mfma_f32_16x16x32_bf16(a, bfg, accg[nt], 0, 0, 0);
        }
    }

    // ---- gated = interaction * sigmoid(gate_pre), kept in registers ----
    // g[nt][r] lives for row 4*quad+r, col nt*16+cn.
    float g[4][4];
#pragma unroll
    for (int nt = 0; nt < 4; ++nt)
#pragma unroll
        for (int r = 0; r < 4; ++r)
            g[nt][r] = acc2[nt][r] / (1.0f + __expf(-accg[nt][r]));

    // ---- segmented reduction in registers; flush via cross-quad butterfly ----
    {
        const int rbase = 16 * w;
        float part0 = 0.f, part1 = 0.f, part2 = 0.f, part3 = 0.f;
        int   segSrc = srcIds[rbase];
        int   segRow = 0;
#pragma unroll
        for (int i = 0; i < 16; ++i) {
            const int s = srcIds[rbase + i];          // wave-uniform
            if (s != segSrc) {
                // flush segment [segRow's src]
                if (segSrc >= 0) {
                    float t0 = part0, t1 = part1, t2 = part2, t3 = part3;
                    t0 += __shfl_xor(t0, 16); t0 += __shfl_xor(t0, 32);
                    t1 += __shfl_xor(t1, 16); t1 += __shfl_xor(t1, 32);
                    t2 += __shfl_xor(t2, 16); t2 += __shfl_xor(t2, 32);
                    t3 += __shfl_xor(t3, 16); t3 += __shfl_xor(t3, 32);
                    const float tot = (quad < 2) ? (quad == 0 ? t0 : t1)
                                                 : (quad == 2 ? t2 : t3);
                    unsafeAtomicAdd(&summed[(size_t)segSrc * D + ln],
                                    tot * rcS[rbase + segRow]);
                }
                part0 = part1 = part2 = part3 = 0.f;
                segSrc = s;
                segRow = i;
            }
            if ((i >> 2) == quad) {                   // this lane holds row i
                part0 += g[0][i & 3];
                part1 += g[1][i & 3];
                part2 += g[2][i & 3];
                part3 += g[3][i & 3];
            }
        }
        if (segSrc >= 0) {
            float t0 = part0, t1 = part1, t2 = part2, t3 = part3;
            t0 += __shfl_xor(t0, 16); t0 += __shfl_xor(t0, 32);
            t1 += __shfl_xor(t1, 16); t1 += __shfl_xor(t1, 32);
            t2 += __shfl_xor(t2, 16); t2 += __shfl_xor(t2, 32);
            t3 += __shfl_xor(t3, 16); t3 += __shfl_xor(t3, 32);
            const float tot = (quad < 2) ? (quad == 0 ? t0 : t1)
                                         : (quad == 2 ? t2 : t3);
            unsafeAtomicAdd(&summed[(size_t)segSrc * D + ln],
                            tot * rcS[rbase + segRow]);
        }
    }
}

extern "C" void kernel_launch(void* const* d_in, const int* in_sizes, int n_in,
                              void* d_out, int out_size, void* d_ws, size_t ws_size,
                              hipStream_t stream) {
    const float* node_emb   = (const float*)d_in[0];
    const int*   edge_index = (const int*)d_in[1];
    const float* W1 = (const float*)d_in[2];
    const float* b1 = (const float*)d_in[3];
    const float* W2 = (const float*)d_in[4];
    const float* b2 = (const float*)d_in[5];
    const float* Wg = (const float*)d_in[6];
    const float* bg = (const float*)d_in[7];

    const int N = in_sizes[0] / D;
    const int E = in_sizes[1] / 2;
    const int total_emb = N * D;

    // ws layout == R5/R7/R8's proven extent (10,034,048 B for N=50000, E=800000):
    // cnt[N] | off[N] | bsum[256] | sorted[E u32] | bgp[64 f32] | wpack[16K bf16] | emb_bf
    int* cnt    = (int*)d_ws;
    int* off    = cnt + N;
    int* bsum   = off + N;
    unsigned* sorted = (unsigned*)(bsum + 256);
    float* bgp  = (float*)(sorted + E);
    ushort_t* wpack  = (ushort_t*)(bgp + 64);
    ushort_t* emb_bf = wpack + NFRAG * 512;

    float* summed = (float*)d_out;

    hipMemsetAsync(cnt, 0, sizeof(int) * (size_t)N, stream);   // must precede prep's hist

    const int cvt_blocks = (total_emb / 8 + 255) / 256;
    const int e4blocks   = ((E + 3) / 4 + 255) / 256;
    const int zblocks    = (total_emb / 4 + 255) / 256;
    prep_kernel<<<64 + cvt_blocks + 1 + e4blocks + zblocks, 256, 0, stream>>>(
        W1, W2, Wg, b2, bg, node_emb, edge_index,
        wpack, bgp, emb_bf, cnt, summed, total_emb, cvt_blocks, e4blocks, E);

    const int nblocks = (N + 255) / 256;   // 196 (must be <= 256 for inline prefix)
    scan_block <<<nblocks, 256, 0, stream>>>(cnt, off, bsum, N);
    scatter_idx<<<e4blocks, 256, 0, stream>>>(edge_index, off, bsum, sorted, E, nblocks);

    const int ntiles = (E + TILE - 1) / TILE;
    edge_mlp_mfma<<<ntiles, BLOCK, 0, stream>>>(emb_bf, sorted, wpack,
                                                b1, b2, bgp, cnt, summed, E);
}